// Round 1
// baseline (137.054 us; speedup 1.0000x reference)
//
#include <hip/hip_runtime.h>
#include <hip/hip_bf16.h>

typedef float f32x4 __attribute__((ext_vector_type(4)));
typedef __bf16 bf16x8 __attribute__((ext_vector_type(8)));

#define MFMA16(a, b, c) __builtin_amdgcn_mfma_f32_16x16x32_bf16((a), (b), (c), 0, 0, 0)

static __device__ __forceinline__ short f2s(float f) {
    __hip_bfloat16 h = __float2bfloat16(f);
    return *reinterpret_cast<short*>(&h);
}

// ---------------------------------------------------------------------------
// Kernel 1: QKV projection.  C[m][n] = x[m][:] . W[n][:] + b[n]
// x: [8192][256] fp32.  W = Wq/Wk/Wv selected by n/256 (grid.y tile of 64 cols
// lies entirely inside one matrix).  Output scattered to Q/K/V ws tensors,
// layout [b*8+h][nq][32] bf16.
// Tile: 128x64, BK=64, 256 threads (2x2 waves, each wave 64x32).
// ---------------------------------------------------------------------------
__global__ __launch_bounds__(256)
void qkv_gemm(const float* __restrict__ x,
              const float* __restrict__ Wq, const float* __restrict__ bq,
              const float* __restrict__ Wk, const float* __restrict__ bk,
              const float* __restrict__ Wv, const float* __restrict__ bv,
              short* __restrict__ Qb, short* __restrict__ Kb, short* __restrict__ Vb)
{
    __shared__ short As[128 * 72];   // stride 72 shorts (144B): 2-way max aliasing
    __shared__ short Bs[64 * 72];

    const int tid = threadIdx.x;
    const int lane = tid & 63;
    const int wid = tid >> 6;
    const int wr = wid >> 1, wc = wid & 1;
    const int g = lane >> 4, li = lane & 15;

    const int m0 = blockIdx.x * 128;
    const int gc0 = blockIdx.y * 64;
    const int mat = gc0 >> 8;
    const float* W    = (mat == 0) ? Wq : (mat == 1) ? Wk : Wv;
    const float* bias = (mat == 0) ? bq : (mat == 1) ? bk : bv;
    short* Out        = (mat == 0) ? Qb : (mat == 1) ? Kb : Vb;
    const int wc0 = gc0 & 255;

    f32x4 acc[4][2] = {};

    const int sr = tid >> 4;         // 0..15
    const int sc4 = (tid & 15) * 4;  // 0..60

    for (int k0 = 0; k0 < 256; k0 += 64) {
        __syncthreads();
#pragma unroll
        for (int it = 0; it < 8; ++it) {
            int row = sr + it * 16;
            float4 v = *reinterpret_cast<const float4*>(&x[(m0 + row) * 256 + k0 + sc4]);
            short4 s4;
            s4.x = f2s(v.x); s4.y = f2s(v.y); s4.z = f2s(v.z); s4.w = f2s(v.w);
            *reinterpret_cast<short4*>(&As[row * 72 + sc4]) = s4;
        }
#pragma unroll
        for (int it = 0; it < 4; ++it) {
            int row = sr + it * 16;
            float4 v = *reinterpret_cast<const float4*>(&W[(wc0 + row) * 256 + k0 + sc4]);
            short4 s4;
            s4.x = f2s(v.x); s4.y = f2s(v.y); s4.z = f2s(v.z); s4.w = f2s(v.w);
            *reinterpret_cast<short4*>(&Bs[row * 72 + sc4]) = s4;
        }
        __syncthreads();
#pragma unroll
        for (int ks = 0; ks < 2; ++ks) {
            const int kb = ks * 32 + g * 8;
            bf16x8 a[4], bfr[2];
#pragma unroll
            for (int i = 0; i < 4; ++i)
                a[i] = *reinterpret_cast<const bf16x8*>(&As[(wr * 64 + i * 16 + li) * 72 + kb]);
#pragma unroll
            for (int j = 0; j < 2; ++j)
                bfr[j] = *reinterpret_cast<const bf16x8*>(&Bs[(wc * 32 + j * 16 + li) * 72 + kb]);
#pragma unroll
            for (int i = 0; i < 4; ++i)
#pragma unroll
                for (int j = 0; j < 2; ++j)
                    acc[i][j] = MFMA16(a[i], bfr[j], acc[i][j]);
        }
    }

    // Epilogue: bias add, scatter to [bh][nq][d] bf16.
#pragma unroll
    for (int j = 0; j < 2; ++j) {
        const int colW = wc0 + wc * 32 + j * 16 + li;
        const int h = colW >> 5, d = colW & 31;
        const float bv_ = bias[colW];
#pragma unroll
        for (int i = 0; i < 4; ++i) {
#pragma unroll
            for (int r = 0; r < 4; ++r) {
                const int row = m0 + wr * 64 + i * 16 + g * 4 + r;
                const int bb = row >> 10, nq = row & 1023;
                Out[((bb * 8 + h) * 1024 + nq) * 32 + d] = f2s(acc[i][j][r] + bv_);
            }
        }
    }
}

// ---------------------------------------------------------------------------
// Kernel 2: edge-biased flash attention.
// Grid: (N/64, B*H).  Block: 256 threads = 4 waves, each wave owns 16 q rows.
// Q fragment register-resident; K, V^T staged in LDS per 64-k tile; online
// softmax (running max/sum per q row, replicated across 16-lane groups).
// P goes through a per-wave padded LDS buffer to re-fragment for PV MFMA.
// ---------------------------------------------------------------------------
__global__ __launch_bounds__(256)
void attn_kernel(const short* __restrict__ Qb, const short* __restrict__ Kb,
                 const short* __restrict__ Vb, const int* __restrict__ adj,
                 const float* __restrict__ edge_emb, short* __restrict__ AO)
{
    __shared__ short Ks[64 * 40];      // [k][d], stride 40 shorts (80B)
    __shared__ short Vt[32 * 72];      // [d][k], stride 72 shorts
    __shared__ short Ps[4][16 * 72];   // per-wave P tile [q][k]

    const int tid = threadIdx.x, lane = tid & 63, wid = tid >> 6;
    const int g = lane >> 4, li = lane & 15;
    const int bh = blockIdx.y, b = bh >> 3, h = bh & 7;
    const int q0 = blockIdx.x * 64 + wid * 16;

    const short* Qh = Qb + bh * (1024 * 32);
    const short* Kh = Kb + bh * (1024 * 32);
    const short* Vh = Vb + bh * (1024 * 32);

    // Q fragment: A-operand, row = li, k = g*8+j  (8 contiguous bf16 = 16B)
    const bf16x8 qf = *reinterpret_cast<const bf16x8*>(&Qh[(q0 + li) * 32 + g * 8]);

    float e[5];
#pragma unroll
    for (int i = 0; i < 5; ++i) e[i] = edge_emb[i * 8 + h];

    float mrow[4], lrow[4];
    f32x4 o[2] = {};
#pragma unroll
    for (int r = 0; r < 4; ++r) { mrow[r] = -1e30f; lrow[r] = 0.f; }

    const float inv_scale = 0.17677669529663687f;  // 1/sqrt(32)
    const f32x4 zero = {};

    const int krow = tid >> 2, kc = (tid & 3) * 8;   // K staging
    const int vk = tid & 63, vd0 = (tid >> 6) * 8;   // V-transpose staging
    short* Pw = &Ps[wid][0];
    const int* adjb = adj + b * 1024 * 1024;

    for (int k0 = 0; k0 < 1024; k0 += 64) {
        __syncthreads();
        // stage K tile (64x32 bf16)
        *reinterpret_cast<int4*>(&Ks[krow * 40 + kc]) =
            *reinterpret_cast<const int4*>(&Kh[(k0 + krow) * 32 + kc]);
        // stage V tile transposed -> Vt[d][k]
        {
            int4 vv = *reinterpret_cast<const int4*>(&Vh[(k0 + vk) * 32 + vd0]);
            short* vs = reinterpret_cast<short*>(&vv);
#pragma unroll
            for (int i = 0; i < 8; ++i) Vt[(vd0 + i) * 72 + vk] = vs[i];
        }
        __syncthreads();

        // S = Q K^T : 4 MFMAs covering 64 k cols
        f32x4 s[4];
#pragma unroll
        for (int kt = 0; kt < 4; ++kt) {
            bf16x8 kf = *reinterpret_cast<const bf16x8*>(&Ks[(kt * 16 + li) * 40 + g * 8]);
            s[kt] = MFMA16(qf, kf, zero);
        }
        // scale + edge bias (adj lookup)
#pragma unroll
        for (int kt = 0; kt < 4; ++kt) {
            const int kcol = k0 + kt * 16 + li;
#pragma unroll
            for (int r = 0; r < 4; ++r) {
                const int q = q0 + g * 4 + r;
                const int a = adjb[q * 1024 + kcol];
                const float bb = (a == 0) ? e[0] : (a == 1) ? e[1] :
                                 (a == 2) ? e[2] : (a == 3) ? e[3] : e[4];
                s[kt][r] = s[kt][r] * inv_scale + bb;
            }
        }
        // online softmax: row max (across 4 regs, then 16-lane group)
        float resc[4];
#pragma unroll
        for (int r = 0; r < 4; ++r) {
            float t = fmaxf(fmaxf(s[0][r], s[1][r]), fmaxf(s[2][r], s[3][r]));
            t = fmaxf(t, __shfl_xor(t, 1, 16));
            t = fmaxf(t, __shfl_xor(t, 2, 16));
            t = fmaxf(t, __shfl_xor(t, 4, 16));
            t = fmaxf(t, __shfl_xor(t, 8, 16));
            const float nm = fmaxf(mrow[r], t);
            resc[r] = __expf(mrow[r] - nm);
            mrow[r] = nm;
        }
        // p = exp(s - m), row sums
#pragma unroll
        for (int r = 0; r < 4; ++r) {
            float rs = 0.f;
#pragma unroll
            for (int kt = 0; kt < 4; ++kt) {
                float p = __expf(s[kt][r] - mrow[r]);
                s[kt][r] = p;
                rs += p;
            }
            rs += __shfl_xor(rs, 1, 16);
            rs += __shfl_xor(rs, 2, 16);
            rs += __shfl_xor(rs, 4, 16);
            rs += __shfl_xor(rs, 8, 16);
            lrow[r] = lrow[r] * resc[r] + rs;
        }
        // rescale O accumulator
#pragma unroll
        for (int dt = 0; dt < 2; ++dt)
#pragma unroll
            for (int r = 0; r < 4; ++r) o[dt][r] *= resc[r];
        // write P (bf16) to per-wave LDS buffer [q_local][k_local]
#pragma unroll
        for (int kt = 0; kt < 4; ++kt)
#pragma unroll
            for (int r = 0; r < 4; ++r)
                Pw[(g * 4 + r) * 72 + kt * 16 + li] = f2s(s[kt][r]);
        // PV: O += P . V   (2 k-subtiles x 2 d-tiles)
#pragma unroll
        for (int ks = 0; ks < 2; ++ks) {
            bf16x8 pf = *reinterpret_cast<const bf16x8*>(&Pw[li * 72 + ks * 32 + g * 8]);
#pragma unroll
            for (int dt = 0; dt < 2; ++dt) {
                bf16x8 vf = *reinterpret_cast<const bf16x8*>(&Vt[(dt * 16 + li) * 72 + ks * 32 + g * 8]);
                o[dt] = MFMA16(pf, vf, o[dt]);
            }
        }
    }

    // finalize: divide by l, write AO [8192][256] bf16 (head-interleaved)
#pragma unroll
    for (int r = 0; r < 4; ++r) {
        const float inv = 1.0f / lrow[r];
        const int q = q0 + g * 4 + r;
        short* dst = &AO[(b * 1024 + q) * 256 + h * 32];
#pragma unroll
        for (int dt = 0; dt < 2; ++dt)
            dst[dt * 16 + li] = f2s(o[dt][r] * inv);
    }
}

// ---------------------------------------------------------------------------
// Kernel 3: output projection.  out[m][n] = AO[m][:] . Wo[n][:] + bo[n], fp32
// ---------------------------------------------------------------------------
__global__ __launch_bounds__(256)
void out_gemm(const short* __restrict__ AO, const float* __restrict__ Wo,
              const float* __restrict__ bo, float* __restrict__ out)
{
    __shared__ short As[128 * 72];
    __shared__ short Bs[64 * 72];

    const int tid = threadIdx.x, lane = tid & 63, wid = tid >> 6;
    const int wr = wid >> 1, wcn = wid & 1;
    const int g = lane >> 4, li = lane & 15;
    const int m0 = blockIdx.x * 128, n0 = blockIdx.y * 64;

    f32x4 acc[4][2] = {};
    const int ar = tid >> 3, ac8 = (tid & 7) * 8;   // A stage (bf16 source)
    const int br = tid >> 4, bc4 = (tid & 15) * 4;  // B stage (fp32 source)

    for (int k0 = 0; k0 < 256; k0 += 64) {
        __syncthreads();
#pragma unroll
        for (int it = 0; it < 4; ++it) {
            int row = ar + it * 32;
            *reinterpret_cast<int4*>(&As[row * 72 + ac8]) =
                *reinterpret_cast<const int4*>(&AO[(m0 + row) * 256 + k0 + ac8]);
        }
#pragma unroll
        for (int it = 0; it < 4; ++it) {
            int row = br + it * 16;
            float4 v = *reinterpret_cast<const float4*>(&Wo[(n0 + row) * 256 + k0 + bc4]);
            short4 s4; s4.x = f2s(v.x); s4.y = f2s(v.y); s4.z = f2s(v.z); s4.w = f2s(v.w);
            *reinterpret_cast<short4*>(&Bs[row * 72 + bc4]) = s4;
        }
        __syncthreads();
#pragma unroll
        for (int ks = 0; ks < 2; ++ks) {
            const int kb = ks * 32 + g * 8;
            bf16x8 a[4], bb[2];
#pragma unroll
            for (int i = 0; i < 4; ++i)
                a[i] = *reinterpret_cast<const bf16x8*>(&As[(wr * 64 + i * 16 + li) * 72 + kb]);
#pragma unroll
            for (int j = 0; j < 2; ++j)
                bb[j] = *reinterpret_cast<const bf16x8*>(&Bs[(wcn * 32 + j * 16 + li) * 72 + kb]);
#pragma unroll
            for (int i = 0; i < 4; ++i)
#pragma unroll
                for (int j = 0; j < 2; ++j)
                    acc[i][j] = MFMA16(a[i], bb[j], acc[i][j]);
        }
    }
#pragma unroll
    for (int j = 0; j < 2; ++j) {
        const int col = n0 + wcn * 32 + j * 16 + li;
        const float bv_ = bo[col];
#pragma unroll
        for (int i = 0; i < 4; ++i)
#pragma unroll
            for (int r = 0; r < 4; ++r) {
                const int row = m0 + wr * 64 + i * 16 + g * 4 + r;
                out[row * 256 + col] = acc[i][j][r] + bv_;
            }
    }
}

extern "C" void kernel_launch(void* const* d_in, const int* in_sizes, int n_in,
                              void* d_out, int out_size, void* d_ws, size_t ws_size,
                              hipStream_t stream)
{
    const float* x  = (const float*)d_in[0];
    const int*   adj = (const int*)d_in[1];
    const float* Wq = (const float*)d_in[2];
    const float* bq = (const float*)d_in[3];
    const float* Wk = (const float*)d_in[4];
    const float* bk = (const float*)d_in[5];
    const float* Wv = (const float*)d_in[6];
    const float* bv = (const float*)d_in[7];
    const float* Wo = (const float*)d_in[8];
    const float* bo = (const float*)d_in[9];
    const float* ee = (const float*)d_in[10];
    float* out = (float*)d_out;

    // Workspace layout (bf16 as short):
    //   Qb/Kb/Vb: [64][1024][32]  (4 MB each)
    //   AO:       [8192][256]     (4 MB)
    short* Qb = (short*)d_ws;
    short* Kb = Qb + 2 * 1024 * 1024;
    short* Vb = Kb + 2 * 1024 * 1024;
    short* AO = Vb + 2 * 1024 * 1024;

    qkv_gemm<<<dim3(64, 12), 256, 0, stream>>>(x, Wq, bq, Wk, bk, Wv, bv, Qb, Kb, Vb);
    attn_kernel<<<dim3(16, 64), 256, 0, stream>>>(Qb, Kb, Vb, adj, ee, AO);
    out_gemm<<<dim3(64, 4), 256, 0, stream>>>(AO, Wo, bo, out);
}

// Round 3
// 83.122 us; speedup vs baseline: 1.6488x; 1.6488x over previous
//
#include <hip/hip_runtime.h>
#include <hip/hip_bf16.h>

typedef float f32x4 __attribute__((ext_vector_type(4)));
typedef float f32x16 __attribute__((ext_vector_type(16)));
typedef __bf16 bf16x8 __attribute__((ext_vector_type(8)));

#define MFMA16(a, b, c) __builtin_amdgcn_mfma_f32_16x16x32_bf16((a), (b), (c), 0, 0, 0)
#define MFMA32(a, b, c) __builtin_amdgcn_mfma_f32_32x32x16_bf16((a), (b), (c), 0, 0, 0)

static __device__ __forceinline__ short f2s(float f) {
    __hip_bfloat16 h = __float2bfloat16(f);
    return *reinterpret_cast<short*>(&h);
}
static __device__ __forceinline__ unsigned int cvtpk(float lo, float hi) {
    unsigned int r;
    asm("v_cvt_pk_bf16_f32 %0, %1, %2" : "=v"(r) : "v"(lo), "v"(hi));
    return r;
}

// ---------------------------------------------------------------------------
// Kernel 0: pack adj int32 -> uint8  (values 0..4)
// ---------------------------------------------------------------------------
__global__ __launch_bounds__(256)
void adj_pack(const int* __restrict__ adj, unsigned char* __restrict__ out)
{
    const int i = blockIdx.x * 256 + threadIdx.x;   // handles 16 ints
    const int4* src = reinterpret_cast<const int4*>(adj) + i * 4;
    int4 a = src[0], b = src[1], c = src[2], d = src[3];
    uint4 o;
    o.x = (unsigned)a.x | ((unsigned)a.y << 8) | ((unsigned)a.z << 16) | ((unsigned)a.w << 24);
    o.y = (unsigned)b.x | ((unsigned)b.y << 8) | ((unsigned)b.z << 16) | ((unsigned)b.w << 24);
    o.z = (unsigned)c.x | ((unsigned)c.y << 8) | ((unsigned)c.z << 16) | ((unsigned)c.w << 24);
    o.w = (unsigned)d.x | ((unsigned)d.y << 8) | ((unsigned)d.z << 16) | ((unsigned)d.w << 24);
    reinterpret_cast<uint4*>(out)[i] = o;
}

// ---------------------------------------------------------------------------
// Kernel 1: QKV projection (unchanged).
// ---------------------------------------------------------------------------
__global__ __launch_bounds__(256)
void qkv_gemm(const float* __restrict__ x,
              const float* __restrict__ Wq, const float* __restrict__ bq,
              const float* __restrict__ Wk, const float* __restrict__ bk,
              const float* __restrict__ Wv, const float* __restrict__ bv,
              short* __restrict__ Qb, short* __restrict__ Kb, short* __restrict__ Vb)
{
    __shared__ short As[128 * 72];
    __shared__ short Bs[64 * 72];

    const int tid = threadIdx.x;
    const int lane = tid & 63;
    const int wid = tid >> 6;
    const int wr = wid >> 1, wc = wid & 1;
    const int g = lane >> 4, li = lane & 15;

    const int m0 = blockIdx.x * 128;
    const int gc0 = blockIdx.y * 64;
    const int mat = gc0 >> 8;
    const float* W    = (mat == 0) ? Wq : (mat == 1) ? Wk : Wv;
    const float* bias = (mat == 0) ? bq : (mat == 1) ? bk : bv;
    short* Out        = (mat == 0) ? Qb : (mat == 1) ? Kb : Vb;
    const int wc0 = gc0 & 255;

    f32x4 acc[4][2] = {};

    const int sr = tid >> 4;
    const int sc4 = (tid & 15) * 4;

    for (int k0 = 0; k0 < 256; k0 += 64) {
        __syncthreads();
#pragma unroll
        for (int it = 0; it < 8; ++it) {
            int row = sr + it * 16;
            float4 v = *reinterpret_cast<const float4*>(&x[(m0 + row) * 256 + k0 + sc4]);
            short4 s4;
            s4.x = f2s(v.x); s4.y = f2s(v.y); s4.z = f2s(v.z); s4.w = f2s(v.w);
            *reinterpret_cast<short4*>(&As[row * 72 + sc4]) = s4;
        }
#pragma unroll
        for (int it = 0; it < 4; ++it) {
            int row = sr + it * 16;
            float4 v = *reinterpret_cast<const float4*>(&W[(wc0 + row) * 256 + k0 + sc4]);
            short4 s4;
            s4.x = f2s(v.x); s4.y = f2s(v.y); s4.z = f2s(v.z); s4.w = f2s(v.w);
            *reinterpret_cast<short4*>(&Bs[row * 72 + sc4]) = s4;
        }
        __syncthreads();
#pragma unroll
        for (int ks = 0; ks < 2; ++ks) {
            const int kb = ks * 32 + g * 8;
            bf16x8 a[4], bfr[2];
#pragma unroll
            for (int i = 0; i < 4; ++i)
                a[i] = *reinterpret_cast<const bf16x8*>(&As[(wr * 64 + i * 16 + li) * 72 + kb]);
#pragma unroll
            for (int j = 0; j < 2; ++j)
                bfr[j] = *reinterpret_cast<const bf16x8*>(&Bs[(wc * 32 + j * 16 + li) * 72 + kb]);
#pragma unroll
            for (int i = 0; i < 4; ++i)
#pragma unroll
                for (int j = 0; j < 2; ++j)
                    acc[i][j] = MFMA16(a[i], bfr[j], acc[i][j]);
        }
    }

#pragma unroll
    for (int j = 0; j < 2; ++j) {
        const int colW = wc0 + wc * 32 + j * 16 + li;
        const int h = colW >> 5, d = colW & 31;
        const float bv_ = bias[colW];
#pragma unroll
        for (int i = 0; i < 4; ++i) {
#pragma unroll
            for (int r = 0; r < 4; ++r) {
                const int row = m0 + wr * 64 + i * 16 + g * 4 + r;
                const int bb = row >> 10, nq = row & 1023;
                Out[((bb * 8 + h) * 1024 + nq) * 32 + d] = f2s(acc[i][j][r] + bv_);
            }
        }
    }
}

// ---------------------------------------------------------------------------
// Kernel 2: edge-biased flash attention, 32x32 swapped-operand structure.
// Grid: (32, 64).  Block: 128 threads = 2 waves.  Split-k across waves.
// Merge scratch now lives inside each wave's OWN V^T region (no cross-wave
// overlap; was the round-2 NaN race).
// ---------------------------------------------------------------------------
__global__ __launch_bounds__(128, 4)
void attn2(const short* __restrict__ Qb, const short* __restrict__ Kb,
           const short* __restrict__ Vb, const unsigned char* __restrict__ adj8,
           const float* __restrict__ edge_emb, short* __restrict__ AO)
{
    // per-wave: 2 buffers of V^T [32 d][72 stride] shorts (4608 shorts/wave)
    __shared__ __align__(16) short Vsh[2 * 2 * 2304];   // 18.4 KB

    const int tid = threadIdx.x, lane = tid & 63, wid = tid >> 6;
    const int l5 = lane & 31, h32 = lane >> 5;
    const int bh = blockIdx.y, b = bh >> 3, h = bh & 7;
    const int q = blockIdx.x * 32 + l5;

    const short* Qh = Qb + bh * (1024 * 32);
    const short* Kh = Kb + bh * (1024 * 32);
    const short* Vh = Vb + bh * (1024 * 32);
    const unsigned char* adjq = adj8 + (size_t)b * (1024 * 1024) + (size_t)q * 1024;

    // Q fragments (B-operand): col=q=l5, k(d) = c*16 + h32*8 + j
    const bf16x8 qf0 = *reinterpret_cast<const bf16x8*>(&Qh[q * 32 + h32 * 8]);
    const bf16x8 qf1 = *reinterpret_cast<const bf16x8*>(&Qh[q * 32 + 16 + h32 * 8]);

    float eb[5];
#pragma unroll
    for (int i = 0; i < 5; ++i) eb[i] = edge_emb[i * 8 + h];

    const float inv_scale = 0.17677669529663687f;   // 1/sqrt(32)
    const f32x16 zero16 = {};

    f32x16 o = {};
    float m_run = -1e30f, l_run = 0.f;

    short* Vt = &Vsh[wid * 2 * 2304];
    const int T0 = wid * 8;

    // prologue: stage V^T tile T0 into buf 0 (lane = k-row)
    {
        const int kr = T0 * 64 + lane;
#pragma unroll
        for (int p = 0; p < 4; ++p) {
            int4 v = *reinterpret_cast<const int4*>(&Vh[kr * 32 + p * 8]);
            const short* vs = reinterpret_cast<const short*>(&v);
#pragma unroll
            for (int i = 0; i < 8; ++i) Vt[(p * 8 + i) * 72 + lane] = vs[i];
        }
    }

    int cur = 0;
    for (int t = 0; t < 8; ++t) {
        const int k0 = (T0 + t) * 64;

        // prefetch next V tile into registers
        int4 vload[4];
        if (t < 7) {
            const int kr = (k0 + 64) + lane;
#pragma unroll
            for (int p = 0; p < 4; ++p)
                vload[p] = *reinterpret_cast<const int4*>(&Vh[kr * 32 + p * 8]);
        }
        // adj byte loads (4 codes per load), issued early
        unsigned int a4[8];
#pragma unroll
        for (int ks = 0; ks < 2; ++ks)
#pragma unroll
            for (int rg = 0; rg < 4; ++rg)
                a4[ks * 4 + rg] = *reinterpret_cast<const unsigned int*>(
                    &adjq[k0 + ks * 32 + rg * 8 + h32 * 4]);

        // QK^T swapped: S^T[k][q], k-local = (reg&3)+8*(reg>>2)+4*h32, q = l5
        f32x16 s[2];
#pragma unroll
        for (int ks = 0; ks < 2; ++ks) {
            const int krow = k0 + ks * 32 + l5;
            bf16x8 kfa = *reinterpret_cast<const bf16x8*>(&Kh[krow * 32 + h32 * 8]);
            bf16x8 kfb = *reinterpret_cast<const bf16x8*>(&Kh[krow * 32 + 16 + h32 * 8]);
            s[ks] = MFMA32(kfa, qf0, zero16);
            s[ks] = MFMA32(kfb, qf1, s[ks]);
        }

        // tile max over this lane's 32 scores, then merge with partner half
        float tm = s[0][0];
#pragma unroll
        for (int ks = 0; ks < 2; ++ks)
#pragma unroll
            for (int r = 0; r < 16; ++r) tm = fmaxf(tm, s[ks][r]);
        tm = fmaxf(tm, __shfl_xor(tm, 32));

        const float m_new = fmaxf(m_run, tm * inv_scale);
        const float resc = __expf(m_run - m_new);
        m_run = m_new;

        float wm[5];
#pragma unroll
        for (int i = 0; i < 5; ++i) wm[i] = eb[i] - m_new;

        // p = exp(s*inv_scale - m + eb[adj]); pack into bf16 words immediately
        unsigned int pw[2][8];
        float lsum = 0.f;
#pragma unroll
        for (int ks = 0; ks < 2; ++ks) {
#pragma unroll
            for (int rg = 0; rg < 4; ++rg) {
                const unsigned int aw = a4[ks * 4 + rg];
                float pv[4];
#pragma unroll
                for (int j = 0; j < 4; ++j) {
                    const unsigned int a = (aw >> (j * 8)) & 0xFF;
                    const float base = (a == 0) ? wm[0] : (a == 1) ? wm[1] :
                                       (a == 2) ? wm[2] : (a == 3) ? wm[3] : wm[4];
                    const float pp = __expf(fmaf(s[ks][rg * 4 + j], inv_scale, base));
                    pv[j] = pp;
                    lsum += pp;
                }
                pw[ks][rg * 2 + 0] = cvtpk(pv[0], pv[1]);
                pw[ks][rg * 2 + 1] = cvtpk(pv[2], pv[3]);
            }
        }
        lsum += __shfl_xor(lsum, 32);
        l_run = l_run * resc + lsum;

        // rescale O accumulator (per-lane uniform: O^T col = q)
#pragma unroll
        for (int r = 0; r < 16; ++r) o[r] *= resc;

        // stage next V^T into other buffer
        if (t < 7) {
            short* dst = Vt + (cur ^ 1) * 2304;
#pragma unroll
            for (int p = 0; p < 4; ++p) {
                const short* vs = reinterpret_cast<const short*>(&vload[p]);
#pragma unroll
                for (int i = 0; i < 8; ++i) dst[(p * 8 + i) * 72 + lane] = vs[i];
            }
        }

        // PV: O^T += V^T . P^T  (4 mfmas, K=16 each)
#pragma unroll
        for (int kc = 0; kc < 4; ++kc) {
            const int ks = kc >> 1, half = kc & 1;
            const unsigned int A0 = pw[ks][4 * half + 0], A1 = pw[ks][4 * half + 1];
            const unsigned int B0 = pw[ks][4 * half + 2], B1 = pw[ks][4 * half + 3];
            const unsigned int send0 = h32 ? A0 : B0, send1 = h32 ? A1 : B1;
            const unsigned int rv0 = __shfl_xor(send0, 32);
            const unsigned int rv1 = __shfl_xor(send1, 32);
            const unsigned int own0 = h32 ? B0 : A0, own1 = h32 ? B1 : A1;
            union { unsigned int u[4]; bf16x8 v; } P;
            P.u[0] = h32 ? rv0 : own0;
            P.u[1] = h32 ? rv1 : own1;
            P.u[2] = h32 ? own0 : rv0;
            P.u[3] = h32 ? own1 : rv1;
            bf16x8 vf = *reinterpret_cast<const bf16x8*>(
                &Vt[cur * 2304 + l5 * 72 + kc * 16 + h32 * 8]);
            o = MFMA32(vf, P.v, o);
        }
        cur ^= 1;
    }

    // ---- split-k flash merge: scratch inside each wave's OWN Vt region ----
    // wave w region: shorts [w*4608, w*4608+4608) -> floats [w*2304, +2304);
    // need 1408 floats (m[64], l[64], o[64*20]) -> fits, no cross-wave overlap.
    float* mg = reinterpret_cast<float*>(Vsh);
    float* base = mg + wid * 2304;
    base[lane] = m_run;
    base[64 + lane] = l_run;
#pragma unroll
    for (int r = 0; r < 16; ++r) base[128 + lane * 20 + r] = o[r];
    __syncthreads();

    if (wid == 0) {
        const float* pb = mg + 2304;
        const float m1 = pb[lane], l1 = pb[64 + lane];
        const float mM = fmaxf(m_run, m1);
        const float a0 = __expf(m_run - mM), a1 = __expf(m1 - mM);
        const float lM = l_run * a0 + l1 * a1;
        const float inv = 1.0f / lM;
        short* dst = &AO[((size_t)(b * 1024 + q)) * 256 + h * 32];
#pragma unroll
        for (int rg = 0; rg < 4; ++rg) {
            float v0 = (o[rg * 4 + 0] * a0 + pb[128 + lane * 20 + rg * 4 + 0] * a1) * inv;
            float v1 = (o[rg * 4 + 1] * a0 + pb[128 + lane * 20 + rg * 4 + 1] * a1) * inv;
            float v2 = (o[rg * 4 + 2] * a0 + pb[128 + lane * 20 + rg * 4 + 2] * a1) * inv;
            float v3 = (o[rg * 4 + 3] * a0 + pb[128 + lane * 20 + rg * 4 + 3] * a1) * inv;
            short4 s4; s4.x = f2s(v0); s4.y = f2s(v1); s4.z = f2s(v2); s4.w = f2s(v3);
            *reinterpret_cast<short4*>(&dst[rg * 8 + h32 * 4]) = s4;
        }
    }
}

// ---------------------------------------------------------------------------
// Kernel 3: output projection (unchanged).
// ---------------------------------------------------------------------------
__global__ __launch_bounds__(256)
void out_gemm(const short* __restrict__ AO, const float* __restrict__ Wo,
              const float* __restrict__ bo, float* __restrict__ out)
{
    __shared__ short As[128 * 72];
    __shared__ short Bs[64 * 72];

    const int tid = threadIdx.x, lane = tid & 63, wid = tid >> 6;
    const int wr = wid >> 1, wcn = wid & 1;
    const int g = lane >> 4, li = lane & 15;
    const int m0 = blockIdx.x * 128, n0 = blockIdx.y * 64;

    f32x4 acc[4][2] = {};
    const int ar = tid >> 3, ac8 = (tid & 7) * 8;
    const int br = tid >> 4, bc4 = (tid & 15) * 4;

    for (int k0 = 0; k0 < 256; k0 += 64) {
        __syncthreads();
#pragma unroll
        for (int it = 0; it < 4; ++it) {
            int row = ar + it * 32;
            *reinterpret_cast<int4*>(&As[row * 72 + ac8]) =
                *reinterpret_cast<const int4*>(&AO[(m0 + row) * 256 + k0 + ac8]);
        }
#pragma unroll
        for (int it = 0; it < 4; ++it) {
            int row = br + it * 16;
            float4 v = *reinterpret_cast<const float4*>(&Wo[(n0 + row) * 256 + k0 + bc4]);
            short4 s4; s4.x = f2s(v.x); s4.y = f2s(v.y); s4.z = f2s(v.z); s4.w = f2s(v.w);
            *reinterpret_cast<short4*>(&Bs[row * 72 + bc4]) = s4;
        }
        __syncthreads();
#pragma unroll
        for (int ks = 0; ks < 2; ++ks) {
            const int kb = ks * 32 + g * 8;
            bf16x8 a[4], bb[2];
#pragma unroll
            for (int i = 0; i < 4; ++i)
                a[i] = *reinterpret_cast<const bf16x8*>(&As[(wr * 64 + i * 16 + li) * 72 + kb]);
#pragma unroll
            for (int j = 0; j < 2; ++j)
                bb[j] = *reinterpret_cast<const bf16x8*>(&Bs[(wcn * 32 + j * 16 + li) * 72 + kb]);
#pragma unroll
            for (int i = 0; i < 4; ++i)
#pragma unroll
                for (int j = 0; j < 2; ++j)
                    acc[i][j] = MFMA16(a[i], bb[j], acc[i][j]);
        }
    }
#pragma unroll
    for (int j = 0; j < 2; ++j) {
        const int col = n0 + wcn * 32 + j * 16 + li;
        const float bv_ = bo[col];
#pragma unroll
        for (int i = 0; i < 4; ++i)
#pragma unroll
            for (int r = 0; r < 4; ++r) {
                const int row = m0 + wr * 64 + i * 16 + g * 4 + r;
                out[row * 256 + col] = acc[i][j][r] + bv_;
            }
    }
}

extern "C" void kernel_launch(void* const* d_in, const int* in_sizes, int n_in,
                              void* d_out, int out_size, void* d_ws, size_t ws_size,
                              hipStream_t stream)
{
    const float* x  = (const float*)d_in[0];
    const int*   adj = (const int*)d_in[1];
    const float* Wq = (const float*)d_in[2];
    const float* bq = (const float*)d_in[3];
    const float* Wk = (const float*)d_in[4];
    const float* bk = (const float*)d_in[5];
    const float* Wv = (const float*)d_in[6];
    const float* bv = (const float*)d_in[7];
    const float* Wo = (const float*)d_in[8];
    const float* bo = (const float*)d_in[9];
    const float* ee = (const float*)d_in[10];
    float* out = (float*)d_out;

    // Workspace: Qb/Kb/Vb [64][1024][32] bf16 (4MB each), AO [8192][256] bf16 (4MB),
    // adj8 [8][1024][1024] u8 (8MB)  -> 24MB total
    short* Qb = (short*)d_ws;
    short* Kb = Qb + 2 * 1024 * 1024;
    short* Vb = Kb + 2 * 1024 * 1024;
    short* AO = Vb + 2 * 1024 * 1024;
    unsigned char* adj8 = (unsigned char*)(AO + 2 * 1024 * 1024);

    adj_pack<<<2048, 256, 0, stream>>>(adj, adj8);
    qkv_gemm<<<dim3(64, 12), 256, 0, stream>>>(x, Wq, bq, Wk, bk, Wv, bv, Qb, Kb, Vb);
    attn2<<<dim3(32, 64), 128, 0, stream>>>(Qb, Kb, Vb, adj8, ee, AO);
    out_gemm<<<dim3(64, 4), 256, 0, stream>>>(AO, Wo, bo, out);
}